// Round 1
// baseline (3701.531 us; speedup 1.0000x reference)
//
#include <hip/hip_runtime.h>
#include <cstdint>
#include <cstddef>

// ---------------------------------------------------------------------------
// PortOpt_DL_DeepSig: BN -> aug1(conv5->relu->conv1 | orig | time) ->
//   depth-3 streamed signature (14ch) -> conv5(2954->64) [the big GEMM] ->
//   relu -> conv1(64->8) | time -> depth-3 signature (9ch) -> linear -> softmax
// Round 1: full fp32, tiled vector-FMA GEMM. MFMA comes later.
// ---------------------------------------------------------------------------

#define BATCH 128
#define LSEQ  256
#define CIN   8
#define L1P   252     // path1 length
#define NS1   251     // stream rows (increments of path1)
#define SC1   2954    // 14 + 196 + 2744
#define TOUT  247     // stage-2 conv output positions
#define OCH   64
#define SC2   819     // 9 + 81 + 729
#define NSTK  50

// ---------------- BN stats: per-l mean/var over (b,c) ----------------------
__global__ __launch_bounds__(256) void k_bn(const float* __restrict__ x,
                                            const float* __restrict__ gamma,
                                            const float* __restrict__ beta,
                                            float* __restrict__ scale,
                                            float* __restrict__ shift) {
  int l = blockIdx.x, tid = threadIdx.x;
  float s = 0.f, q = 0.f;
#pragma unroll
  for (int p = 0; p < 4; ++p) {
    int e = tid + p * 256;              // e < 1024 = B*CIN
    int b = e >> 3, c = e & 7;
    float v = x[((size_t)b * LSEQ + l) * CIN + c];
    s += v; q += v * v;
  }
  for (int d = 32; d; d >>= 1) { s += __shfl_xor(s, d); q += __shfl_xor(q, d); }
  __shared__ float ss[4], qq[4];
  int w = tid >> 6;
  if ((tid & 63) == 0) { ss[w] = s; qq[w] = q; }
  __syncthreads();
  if (tid == 0) {
    float S = ss[0] + ss[1] + ss[2] + ss[3];
    float Q = qq[0] + qq[1] + qq[2] + qq[3];
    float mean = S * (1.f / 1024.f);
    float var  = Q * (1.f / 1024.f) - mean * mean;
    float istd = 1.0f / sqrtf(var + 1e-5f);
    float sc = istd * gamma[l];
    scale[l] = sc;
    shift[l] = beta[l] - mean * sc;
  }
}

// ---------------- Augment 1: build path1 (B, 252, 14) ----------------------
__global__ __launch_bounds__(256) void k_aug1(const float* __restrict__ x,
                                              const float* __restrict__ scale,
                                              const float* __restrict__ shift,
                                              const float* __restrict__ w1,
                                              const float* __restrict__ b1,
                                              const float* __restrict__ w2,
                                              const float* __restrict__ b2,
                                              float* __restrict__ P1) {
  __shared__ float w1s[400], b1s[10], w2s[50], b2s[5];
  int tid = threadIdx.x;
  for (int i = tid; i < 400; i += 256) w1s[i] = w1[i];
  if (tid < 10) b1s[tid] = b1[tid];
  if (tid < 50) w2s[tid] = w2[tid];
  if (tid < 5)  b2s[tid] = b2[tid];
  __syncthreads();
  int g = blockIdx.x * 256 + tid;
  if (g >= BATCH * L1P) return;
  int b = g / L1P, t = g % L1P;
  float xn[5][8];
#pragma unroll
  for (int k = 0; k < 5; ++k) {
    int l = t + k;
    float sc = scale[l], sh = shift[l];
#pragma unroll
    for (int c = 0; c < 8; ++c)
      xn[k][c] = x[((size_t)b * LSEQ + l) * CIN + c] * sc + sh;
  }
  float r10[10];
#pragma unroll
  for (int co = 0; co < 10; ++co) {
    float s = b1s[co];
#pragma unroll
    for (int c = 0; c < 8; ++c)
#pragma unroll
      for (int k = 0; k < 5; ++k)
        s += xn[k][c] * w1s[co * 40 + c * 5 + k];
    r10[co] = fmaxf(s, 0.f);
  }
  float* o = P1 + ((size_t)b * L1P + t) * 14;
#pragma unroll
  for (int c = 0; c < 8; ++c) o[c] = xn[4][c];
  o[8] = (float)t * (1.0f / 251.0f);
#pragma unroll
  for (int oo = 0; oo < 5; ++oo) {
    float s = b2s[oo];
#pragma unroll
    for (int co = 0; co < 10; ++co) s += r10[co] * w2s[oo * 10 + co];
    o[9 + oo] = s;
  }
}

// ---------------- transform W: (64, 2954, 5) -> Wt[k][c][o] ----------------
__global__ __launch_bounds__(256) void k_wt(const float* __restrict__ w,
                                            float* __restrict__ Wt) {
  int idx = blockIdx.x * 256 + threadIdx.x;
  if (idx >= 5 * SC1 * OCH) return;
  int k = idx / (SC1 * OCH);
  int rem = idx % (SC1 * OCH);
  int c = rem / OCH, o = rem % OCH;
  Wt[idx] = w[((size_t)o * SC1 + c) * 5 + k];
}

// ---------------- streamed depth-3 signature scan (chunked, ring buf) ------
__global__ __launch_bounds__(256) void k_scan(const float* __restrict__ P1,
                                              float* __restrict__ S,
                                              float* __restrict__ carry,
                                              int gr0, int steps, int NR) {
  int b = blockIdx.x, tid = threadIdx.x;
  const float* p = P1 + (size_t)b * L1P * 14;
  float* Sb = S + (size_t)b * NR * SC1;
  float* cb = carry + (size_t)b * SC1;
  __shared__ float a1s[14], a2s[196], vs[2][14], b2s[2][196];
  float a3[11];
  int ia[11], i2[11], il2[11], ik[11];
#pragma unroll
  for (int n = 0; n < 11; ++n) {
    int e = tid + n * 256;
    ia[n] = e / 196; i2[n] = e / 14; il2[n] = e % 196; ik[n] = e % 14;
  }
  if (gr0 > 0) {
    if (tid < 14)  a1s[tid] = cb[tid];
    if (tid < 196) a2s[tid] = cb[14 + tid];
#pragma unroll
    for (int n = 0; n < 11; ++n) { int e = tid + n * 256; if (e < 2744) a3[n] = cb[210 + e]; }
  }
  { // prep v, b2 for first step r = gr0
    int r = gr0;
    if (tid < 14) vs[0][tid] = p[(r + 1) * 14 + tid] - p[r * 14 + tid];
    if (tid < 196) {
      int j = tid / 14, k = tid % 14;
      float vj = p[(r + 1) * 14 + j] - p[r * 14 + j];
      float vk = p[(r + 1) * 14 + k] - p[r * 14 + k];
      b2s[0][tid] = 0.5f * vj * vk;
    }
  }
  __syncthreads();
  for (int s = 0; s < steps; ++s) {
    int r = gr0 + s, buf = s & 1;
    float c1n = 0.f, c2n = 0.f;
    if (r == 0) {                        // init = exp3(dx0)
      if (tid < 14)  c1n = vs[buf][tid];
      if (tid < 196) c2n = b2s[buf][tid];
#pragma unroll
      for (int n = 0; n < 11; ++n) {
        int e = tid + n * 256;
        if (e < 2744) a3[n] = vs[buf][ia[n]] * b2s[buf][il2[n]] * (1.f / 3.f);
      }
    } else {                             // chen(carry, exp3(v))
#pragma unroll
      for (int n = 0; n < 11; ++n) {
        int e = tid + n * 256;
        if (e < 2744)
          a3[n] += (a1s[ia[n]] + vs[buf][ia[n]] * (1.f / 3.f)) * b2s[buf][il2[n]]
                 + a2s[i2[n]] * vs[buf][ik[n]];
      }
      if (tid < 196) c2n = a2s[tid] + b2s[buf][tid] + a1s[tid / 14] * vs[buf][tid % 14];
      if (tid < 14)  c1n = a1s[tid] + vs[buf][tid];
    }
    __syncthreads();
    // commit + stream-row write + prep next v/b2 (all conflict-free)
    if (tid < 14)  a1s[tid] = c1n;
    if (tid < 196) a2s[tid] = c2n;
    {
      int srow = r % NR;
      float* o = Sb + (size_t)srow * SC1;
      if (tid < 14)  o[tid] = c1n;
      if (tid < 196) o[14 + tid] = c2n;
#pragma unroll
      for (int n = 0; n < 11; ++n) { int e = tid + n * 256; if (e < 2744) o[210 + e] = a3[n]; }
    }
    if (s + 1 < steps) {
      int r2 = r + 1, nb = buf ^ 1;
      if (tid < 14) vs[nb][tid] = p[(r2 + 1) * 14 + tid] - p[r2 * 14 + tid];
      if (tid < 196) {
        int j = tid / 14, k = tid % 14;
        float vj = p[(r2 + 1) * 14 + j] - p[r2 * 14 + j];
        float vk = p[(r2 + 1) * 14 + k] - p[r2 * 14 + k];
        b2s[nb][tid] = 0.5f * vj * vk;
      }
    }
    __syncthreads();
  }
  if (tid < 14)  cb[tid] = a1s[tid];
  if (tid < 196) cb[14 + tid] = a2s[tid];
#pragma unroll
  for (int n = 0; n < 11; ++n) { int e = tid + n * 256; if (e < 2744) cb[210 + e] = a3[n]; }
}

// ---------------- the big conv-as-GEMM: C1[b,t,o] = sum_k sum_c S[t+k,c]Wt[k,c,o]
// tile: 64 t x 64 o per block, 256 threads, thread = 4t x 4o.
__global__ __launch_bounds__(256) void k_gemm(const float* __restrict__ S,
                                              const float* __restrict__ Wt,
                                              const float* __restrict__ b1,
                                              float* __restrict__ C1,
                                              int out_base, int n_out, int NR) {
  int b = blockIdx.y;
  int out0 = out_base + blockIdx.x * 64;
  int tid = threadIdx.x, tx = tid & 15, ty = tid >> 4;
  __shared__ __align__(16) float s_lds[32 * 76];      // [c][row], row-stride 76 (pad)
  __shared__ __align__(16) float w_lds[5 * 32 * 64];  // [k][c][o]
  __shared__ int rowmap[68];
  if (tid < 68) rowmap[tid] = (out0 + tid) % NR;
  float acc[4][4] = {};
  const float* Sb = S + (size_t)b * NR * SC1;
  __syncthreads();
  for (int cc0 = 0; cc0 < SC1; cc0 += 32) {
    int ccn = min(32, SC1 - cc0);
    { // stage S: 68 rows x ccn cols, transposed into LDS
      int c = tid & 31, r0 = tid >> 5;
      if (c < ccn) {
#pragma unroll
        for (int pp = 0; pp < 9; ++pp) {
          int row = r0 + pp * 8;
          if (row < 68)
            s_lds[c * 76 + row] = Sb[(size_t)rowmap[row] * SC1 + cc0 + c];
        }
      }
    }
    // stage W: all 5 taps for this c-chunk
    for (int idx = tid; idx < 5 * 32 * 64; idx += 256) {
      int k = idx >> 11;
      int rem = idx & 2047;
      int c = rem >> 6, o = rem & 63;
      w_lds[idx] = (c < ccn) ? Wt[((size_t)k * SC1 + cc0 + c) * OCH + o] : 0.f;
    }
    __syncthreads();
    for (int c = 0; c < ccn; ++c) {
      const float4 s0 = *(const float4*)&s_lds[c * 76 + ty * 4];
      const float4 s1 = *(const float4*)&s_lds[c * 76 + ty * 4 + 4];
      float sw[8] = {s0.x, s0.y, s0.z, s0.w, s1.x, s1.y, s1.z, s1.w};
#pragma unroll
      for (int k = 0; k < 5; ++k) {
        const float4 w = *(const float4*)&w_lds[(k * 32 + c) * 64 + tx * 4];
#pragma unroll
        for (int i = 0; i < 4; ++i) {
          float sv = sw[k + i];
          acc[i][0] += sv * w.x; acc[i][1] += sv * w.y;
          acc[i][2] += sv * w.z; acc[i][3] += sv * w.w;
        }
      }
    }
    __syncthreads();
  }
  float bias0 = b1[tx * 4], bias1 = b1[tx * 4 + 1], bias2 = b1[tx * 4 + 2], bias3 = b1[tx * 4 + 3];
#pragma unroll
  for (int i = 0; i < 4; ++i) {
    int lo = ty * 4 + i;
    if (blockIdx.x * 64 + lo < n_out) {
      int t = out0 + lo;
      float4 v;
      v.x = acc[i][0] + bias0; v.y = acc[i][1] + bias1;
      v.z = acc[i][2] + bias2; v.w = acc[i][3] + bias3;
      *(float4*)&C1[((size_t)b * TOUT + t) * OCH + tx * 4] = v;
    }
  }
}

// ---------------- P2: relu(C1) @ w2 + b2, plus time channel ----------------
__global__ __launch_bounds__(256) void k_p2(const float* __restrict__ C1,
                                            const float* __restrict__ w2,
                                            const float* __restrict__ b2,
                                            float* __restrict__ P2) {
  int warp = blockIdx.x * 4 + (threadIdx.x >> 6);
  int lane = threadIdx.x & 63;
  int b = warp / TOUT, t = warp % TOUT;
  float v = fmaxf(C1[((size_t)b * TOUT + t) * OCH + lane], 0.f);
  float* o = P2 + ((size_t)b * TOUT + t) * 9;
#pragma unroll
  for (int oo = 0; oo < 8; ++oo) {
    float s = v * w2[oo * 64 + lane];
    for (int d = 32; d; d >>= 1) s += __shfl_xor(s, d);
    if (lane == oo) o[1 + oo] = s + b2[oo];
  }
  if (lane == 8) o[0] = (float)t * (1.0f / 246.0f);
}

// ---------------- final depth-3 signature (9ch, no stream) -----------------
__global__ __launch_bounds__(256) void k_sig2(const float* __restrict__ P2,
                                              float* __restrict__ sg) {
  int b = blockIdx.x, tid = threadIdx.x;
  const float* p = P2 + (size_t)b * TOUT * 9;
  __shared__ float a1s[9], a2s[81], vs[2][9], b2s[2][81];
  float a3[3];
  int ia[3], i2[3], il2[3], ik[3];
#pragma unroll
  for (int n = 0; n < 3; ++n) {
    int e = tid + n * 256;
    ia[n] = e / 81; i2[n] = e / 9; il2[n] = e % 81; ik[n] = e % 9;
  }
  if (tid < 9) vs[0][tid] = p[9 + tid] - p[tid];
  if (tid < 81) {
    int j = tid / 9, k = tid % 9;
    b2s[0][tid] = 0.5f * (p[9 + j] - p[j]) * (p[9 + k] - p[k]);
  }
  __syncthreads();
  for (int r = 0; r < 246; ++r) {
    int buf = r & 1;
    float c1n = 0.f, c2n = 0.f;
    if (r == 0) {
      if (tid < 9)  c1n = vs[buf][tid];
      if (tid < 81) c2n = b2s[buf][tid];
#pragma unroll
      for (int n = 0; n < 3; ++n) {
        int e = tid + n * 256;
        if (e < 729) a3[n] = vs[buf][ia[n]] * b2s[buf][il2[n]] * (1.f / 3.f);
      }
    } else {
#pragma unroll
      for (int n = 0; n < 3; ++n) {
        int e = tid + n * 256;
        if (e < 729)
          a3[n] += (a1s[ia[n]] + vs[buf][ia[n]] * (1.f / 3.f)) * b2s[buf][il2[n]]
                 + a2s[i2[n]] * vs[buf][ik[n]];
      }
      if (tid < 81) c2n = a2s[tid] + b2s[buf][tid] + a1s[tid / 9] * vs[buf][tid % 9];
      if (tid < 9)  c1n = a1s[tid] + vs[buf][tid];
    }
    __syncthreads();
    if (tid < 9)  a1s[tid] = c1n;
    if (tid < 81) a2s[tid] = c2n;
    if (r + 1 < 246) {
      int r2 = r + 1, nb = buf ^ 1;
      if (tid < 9) vs[nb][tid] = p[(r2 + 1) * 9 + tid] - p[r2 * 9 + tid];
      if (tid < 81) {
        int j = tid / 9, k = tid % 9;
        b2s[nb][tid] = 0.5f * (p[(r2 + 1) * 9 + j] - p[r2 * 9 + j])
                            * (p[(r2 + 1) * 9 + k] - p[r2 * 9 + k]);
      }
    }
    __syncthreads();
  }
  float* o = sg + (size_t)b * SC2;
  if (tid < 9)  o[tid] = a1s[tid];
  if (tid < 81) o[9 + tid] = a2s[tid];
#pragma unroll
  for (int n = 0; n < 3; ++n) { int e = tid + n * 256; if (e < 729) o[90 + e] = a3[n]; }
}

// ---------------- linear + softmax -----------------------------------------
__global__ __launch_bounds__(64) void k_final(const float* __restrict__ sg,
                                              const float* __restrict__ lw,
                                              const float* __restrict__ lb,
                                              float* __restrict__ out) {
  int b = blockIdx.x, lane = threadIdx.x;
  float logit = -3.402823466e38f;
  if (lane < NSTK) {
    float s = lb[lane];
    const float* w = lw + (size_t)lane * SC2;
    const float* g = sg + (size_t)b * SC2;
    for (int c = 0; c < SC2; ++c) s += g[c] * w[c];
    logit = s;
  }
  float m = logit;
  for (int d = 32; d; d >>= 1) m = fmaxf(m, __shfl_xor(m, d));
  float e = (lane < NSTK) ? expf(logit - m) : 0.f;
  float sum = e;
  for (int d = 32; d; d >>= 1) sum += __shfl_xor(sum, d);
  if (lane < NSTK) out[(size_t)b * NSTK + lane] = e / sum;
}

// ---------------------------------------------------------------------------
extern "C" void kernel_launch(void* const* d_in, const int* in_sizes, int n_in,
                              void* d_out, int out_size, void* d_ws, size_t ws_size,
                              hipStream_t stream) {
  const float* x      = (const float*)d_in[0];
  const float* gamma  = (const float*)d_in[1];
  const float* beta   = (const float*)d_in[2];
  const float* a1w1   = (const float*)d_in[3];
  const float* a1b1   = (const float*)d_in[4];
  const float* a1w2   = (const float*)d_in[5];
  const float* a1b2   = (const float*)d_in[6];
  const float* a2w1   = (const float*)d_in[7];
  const float* a2b1   = (const float*)d_in[8];
  const float* a2w2   = (const float*)d_in[9];
  const float* a2b2   = (const float*)d_in[10];
  const float* lin_w  = (const float*)d_in[11];
  const float* lin_b  = (const float*)d_in[12];
  float* out = (float*)d_out;

  float* ws = (float*)d_ws;
  const size_t off_scale = 0;
  const size_t off_shift = 256;
  const size_t off_P1    = 512;                       // B*252*14 = 451584
  const size_t off_Wt    = off_P1 + (size_t)BATCH * L1P * 14;     // 945280
  const size_t off_carry = off_Wt + (size_t)5 * SC1 * OCH;        // B*2954
  const size_t off_C1    = off_carry + (size_t)BATCH * SC1;       // B*247*64
  const size_t off_P2    = off_C1 + (size_t)BATCH * TOUT * OCH;   // B*247*9
  const size_t off_sig2  = off_P2 + (size_t)BATCH * TOUT * 9;     // B*819
  const size_t off_S     = off_sig2 + (size_t)BATCH * SC2;

  float* scale = ws + off_scale;
  float* shift = ws + off_shift;
  float* P1    = ws + off_P1;
  float* Wt    = ws + off_Wt;
  float* carry = ws + off_carry;
  float* C1    = ws + off_C1;
  float* P2    = ws + off_P2;
  float* sig2  = ws + off_sig2;
  float* Sbuf  = ws + off_S;

  size_t ws_floats = ws_size / 4;
  long avail = (long)ws_floats - (long)off_S;
  long rows = avail > 0 ? avail / ((long)BATCH * SC1) : 0;
  int NR = rows > 251 ? 251 : (int)rows;
  if (NR < 5) NR = 5;   // below this ws is unusable anyway

  k_bn<<<LSEQ, 256, 0, stream>>>(x, gamma, beta, scale, shift);
  k_aug1<<<(BATCH * L1P) / 256, 256, 0, stream>>>(x, scale, shift, a1w1, a1b1,
                                                  a1w2, a1b2, P1);
  k_wt<<<(5 * SC1 * OCH + 255) / 256, 256, 0, stream>>>(a2w1, Wt);

  int written = 0, outdone = 0;
  bool first = true;
  int safety = 0;
  while (outdone < TOUT && safety++ < 300) {
    int steps = first ? (NS1 < NR ? NS1 : NR)
                      : ((NS1 - written) < (NR - 4) ? (NS1 - written) : (NR - 4));
    k_scan<<<BATCH, 256, 0, stream>>>(P1, Sbuf, carry, written, steps, NR);
    written += steps;
    int nout = first ? (written - 4) : steps;
    int ob = outdone;
    dim3 g((nout + 63) / 64, BATCH);
    k_gemm<<<g, 256, 0, stream>>>(Sbuf, Wt, a2b1, C1, ob, nout, NR);
    outdone += nout;
    first = false;
  }

  k_p2<<<(BATCH * TOUT) / 4, 256, 0, stream>>>(C1, a2w2, a2b2, P2);
  k_sig2<<<BATCH, 256, 0, stream>>>(P2, sig2);
  k_final<<<BATCH, 64, 0, stream>>>(sig2, lin_w, lin_b, out);
}

// Round 3
// 3061.119 us; speedup vs baseline: 1.2092x; 1.2092x over previous
//
#include <hip/hip_runtime.h>
#include <cstdint>
#include <cstddef>

// ---------------------------------------------------------------------------
// PortOpt_DL_DeepSig round 3: ws-adaptive t-windowed pipeline.
//  per window: parallel chunk-local Chen scans -> per-batch prefix fold with
//  carry -> parallel fixup -> bf16 hi/lo MFMA GEMM -> conv1+time.
//  Stream stored packed: uint = (bf16hi<<16)|bf16lo  (fp32-equivalent size).
// ---------------------------------------------------------------------------

#define BATCH 128
#define LSEQ  256
#define CIN   8
#define L1P   252
#define NS1   251
#define SC1   2954    // 14 + 196 + 2744
#define TOUT  247
#define OCH   64
#define SC2   819     // 9 + 81 + 729
#define NSTK  50
#define KFLAT 14770   // 5*2954
#define KP    14784   // padded to 231*64
#define NKCH  231     // K chunks of 64

typedef __attribute__((ext_vector_type(8))) short short8;
typedef __attribute__((ext_vector_type(16))) float f32x16;

__device__ __forceinline__ unsigned int pack2(float x) {
  unsigned int u = __float_as_uint(x);
  unsigned int hi = u >> 16;                       // truncated bf16 hi
  float rem = x - __uint_as_float(hi << 16);       // exact remainder
  unsigned int v = __float_as_uint(rem);
  unsigned int lo = (v + 0x7FFFu + ((v >> 16) & 1u)) >> 16;  // RNE bf16 lo
  return (hi << 16) | lo;
}
__device__ __forceinline__ float unpack2(unsigned int s) {
  return __uint_as_float(s & 0xFFFF0000u) + __uint_as_float(s << 16);
}

// ---------------- BN stats ----------------
__global__ __launch_bounds__(256) void k_bn(const float* __restrict__ x,
                                            const float* __restrict__ gamma,
                                            const float* __restrict__ beta,
                                            float* __restrict__ scale,
                                            float* __restrict__ shift) {
  int l = blockIdx.x, tid = threadIdx.x;
  float s = 0.f, q = 0.f;
#pragma unroll
  for (int p = 0; p < 4; ++p) {
    int e = tid + p * 256;
    int b = e >> 3, c = e & 7;
    float v = x[((size_t)b * LSEQ + l) * CIN + c];
    s += v; q += v * v;
  }
  for (int d = 32; d; d >>= 1) { s += __shfl_xor(s, d); q += __shfl_xor(q, d); }
  __shared__ float ss[4], qq[4];
  int w = tid >> 6;
  if ((tid & 63) == 0) { ss[w] = s; qq[w] = q; }
  __syncthreads();
  if (tid == 0) {
    float S = ss[0] + ss[1] + ss[2] + ss[3];
    float Q = qq[0] + qq[1] + qq[2] + qq[3];
    float mean = S * (1.f / 1024.f);
    float var  = Q * (1.f / 1024.f) - mean * mean;
    float istd = 1.0f / sqrtf(var + 1e-5f);
    float sc = istd * gamma[l];
    scale[l] = sc;
    shift[l] = beta[l] - mean * sc;
  }
}

// ---------------- Augment 1: path1 (B, 252, 14) ----------------
__global__ __launch_bounds__(256) void k_aug1(const float* __restrict__ x,
                                              const float* __restrict__ scale,
                                              const float* __restrict__ shift,
                                              const float* __restrict__ w1,
                                              const float* __restrict__ b1,
                                              const float* __restrict__ w2,
                                              const float* __restrict__ b2,
                                              float* __restrict__ P1) {
  __shared__ float w1s[400], b1s[10], w2s[50], b2s[5];
  int tid = threadIdx.x;
  for (int i = tid; i < 400; i += 256) w1s[i] = w1[i];
  if (tid < 10) b1s[tid] = b1[tid];
  if (tid < 50) w2s[tid] = w2[tid];
  if (tid < 5)  b2s[tid] = b2[tid];
  __syncthreads();
  int g = blockIdx.x * 256 + tid;
  if (g >= BATCH * L1P) return;
  int b = g / L1P, t = g % L1P;
  float xn[5][8];
#pragma unroll
  for (int k = 0; k < 5; ++k) {
    int l = t + k;
    float sc = scale[l], sh = shift[l];
#pragma unroll
    for (int c = 0; c < 8; ++c)
      xn[k][c] = x[((size_t)b * LSEQ + l) * CIN + c] * sc + sh;
  }
  float r10[10];
#pragma unroll
  for (int co = 0; co < 10; ++co) {
    float s = b1s[co];
#pragma unroll
    for (int c = 0; c < 8; ++c)
#pragma unroll
      for (int k = 0; k < 5; ++k)
        s += xn[k][c] * w1s[co * 40 + c * 5 + k];
    r10[co] = fmaxf(s, 0.f);
  }
  float* o = P1 + ((size_t)b * L1P + t) * 14;
#pragma unroll
  for (int c = 0; c < 8; ++c) o[c] = xn[4][c];
  o[8] = (float)t * (1.0f / 251.0f);
#pragma unroll
  for (int oo = 0; oo < 5; ++oo) {
    float s = b2s[oo];
#pragma unroll
    for (int co = 0; co < 10; ++co) s += r10[co] * w2s[oo * 10 + co];
    o[9 + oo] = s;
  }
}

// ---------------- W -> [o][kflat] packed hi/lo uint, zero padded ------------
__global__ __launch_bounds__(256) void k_wt2(const float* __restrict__ w,
                                             unsigned int* __restrict__ Wp) {
  int idx = blockIdx.x * 256 + threadIdx.x;
  if (idx >= OCH * KP) return;
  int o = idx / KP, kf = idx % KP;
  float v = 0.f;
  if (kf < KFLAT) {
    int tap = kf / SC1, c = kf % SC1;
    v = w[((size_t)o * SC1 + c) * 5 + tap];
  }
  Wp[idx] = pack2(v);
}

// ---------------- scan pass A: chunk-local signatures (16 rows/chunk) -------
__global__ __launch_bounds__(256) void k_scanA(const float* __restrict__ P1,
                                               unsigned int* __restrict__ Sw,
                                               int rowStride, int w0, int RW) {
  int s = blockIdx.x, b = blockIdx.y, tid = threadIdx.x;
  int r0 = s * 16;
  int cnt = RW - r0; if (cnt > 16) cnt = 16;
  if (cnt <= 0) return;
  const float* p = P1 + (size_t)b * L1P * 14 + (size_t)(w0 + r0) * 14;
  unsigned int* Sb = Sw + ((size_t)b * rowStride + r0) * SC1;
  __shared__ float a1s[14], a2s[196], vs[2][14], b2s[2][196];
  float a3[11];
  int ia[11], i2[11], il2[11], ik[11];
#pragma unroll
  for (int n = 0; n < 11; ++n) {
    int e = tid + n * 256;
    ia[n] = e / 196; i2[n] = e / 14; il2[n] = e % 196; ik[n] = e % 14;
  }
  if (tid < 14) vs[0][tid] = p[14 + tid] - p[tid];
  if (tid < 196) {
    int j = tid / 14, k = tid % 14;
    b2s[0][tid] = 0.5f * (p[14 + j] - p[j]) * (p[14 + k] - p[k]);
  }
  __syncthreads();
  for (int j = 0; j < cnt; ++j) {
    int buf = j & 1;
    float c1n = 0.f, c2n = 0.f;
    if (j == 0) {
      if (tid < 14)  c1n = vs[buf][tid];
      if (tid < 196) c2n = b2s[buf][tid];
#pragma unroll
      for (int n = 0; n < 11; ++n) {
        int e = tid + n * 256;
        if (e < 2744) a3[n] = vs[buf][ia[n]] * b2s[buf][il2[n]] * (1.f / 3.f);
      }
    } else {
#pragma unroll
      for (int n = 0; n < 11; ++n) {
        int e = tid + n * 256;
        if (e < 2744)
          a3[n] += (a1s[ia[n]] + vs[buf][ia[n]] * (1.f / 3.f)) * b2s[buf][il2[n]]
                 + a2s[i2[n]] * vs[buf][ik[n]];
      }
      if (tid < 196) c2n = a2s[tid] + b2s[buf][tid] + a1s[tid / 14] * vs[buf][tid % 14];
      if (tid < 14)  c1n = a1s[tid] + vs[buf][tid];
    }
    __syncthreads();
    if (tid < 14)  a1s[tid] = c1n;
    if (tid < 196) a2s[tid] = c2n;
    {
      unsigned int* o = Sb + (size_t)j * SC1;
      if (tid < 14)  o[tid] = pack2(c1n);
      if (tid < 196) o[14 + tid] = pack2(c2n);
#pragma unroll
      for (int n = 0; n < 11; ++n) {
        int e = tid + n * 256;
        if (e < 2744) o[210 + e] = pack2(a3[n]);
      }
    }
    if (j + 1 < cnt) {
      int nb = buf ^ 1;
      const float* pj = p + (size_t)(j + 1) * 14;
      if (tid < 14) vs[nb][tid] = pj[14 + tid] - pj[tid];
      if (tid < 196) {
        int jj = tid / 14, kk = tid % 14;
        b2s[nb][tid] = 0.5f * (pj[14 + jj] - pj[jj]) * (pj[14 + kk] - pj[kk]);
      }
    }
    __syncthreads();
  }
}

// ---------------- scan pass B: prefix fold of chunk totals + carry ----------
__global__ __launch_bounds__(256) void k_scanB(const unsigned int* __restrict__ Sw,
                                               float* __restrict__ Pfx,
                                               float* __restrict__ carry,
                                               int rowStride, int RW, int NC, int NCC) {
  int b = blockIdx.x, tid = threadIdx.x;
  __shared__ float a1s[14], a2s[196], b1s[14], b2s[196];
  float a3[11], b3[11];
  int ia[11], i2[11], il2[11], ik[11];
#pragma unroll
  for (int n = 0; n < 11; ++n) {
    int e = tid + n * 256;
    ia[n] = e / 196; i2[n] = e / 14; il2[n] = e % 196; ik[n] = e % 14;
  }
  const unsigned int* Sb = Sw + (size_t)b * rowStride * SC1;
  float* cb = carry + (size_t)b * SC1;
  if (tid < 14)  a1s[tid] = cb[tid];
  if (tid < 196) a2s[tid] = cb[14 + tid];
#pragma unroll
  for (int n = 0; n < 11; ++n) { int e = tid + n * 256; if (e < 2744) a3[n] = cb[210 + e]; }
  __syncthreads();
  for (int s = 0; s < NC; ++s) {
    int cnt = RW - s * 16; if (cnt > 16) cnt = 16;
    const unsigned int* tr = Sb + (size_t)(s * 16 + cnt - 1) * SC1;
    if (tid < 14)  b1s[tid] = unpack2(tr[tid]);
    if (tid < 196) b2s[tid] = unpack2(tr[14 + tid]);
#pragma unroll
    for (int n = 0; n < 11; ++n) { int e = tid + n * 256; if (e < 2744) b3[n] = unpack2(tr[210 + e]); }
    __syncthreads();
    // Pfx[s] := prefix BEFORE absorbing this chunk
    float* ps = Pfx + ((size_t)b * 16 + s) * SC1;
    if (tid < 14)  ps[tid] = a1s[tid];
    if (tid < 196) ps[14 + tid] = a2s[tid];
#pragma unroll
    for (int n = 0; n < 11; ++n) { int e = tid + n * 256; if (e < 2744) ps[210 + e] = a3[n]; }
    // a := chen(a, b)
#pragma unroll
    for (int n = 0; n < 11; ++n) {
      int e = tid + n * 256;
      if (e < 2744) a3[n] += b3[n] + a1s[ia[n]] * b2s[il2[n]] + a2s[i2[n]] * b1s[ik[n]];
    }
    float c1n = 0.f, c2n = 0.f;
    if (tid < 196) c2n = a2s[tid] + b2s[tid] + a1s[tid / 14] * b1s[tid % 14];
    if (tid < 14)  c1n = a1s[tid] + b1s[tid];
    __syncthreads();
    if (tid < 14)  a1s[tid] = c1n;
    if (tid < 196) a2s[tid] = c2n;
    if (s == NCC - 1) {   // new carry = signature through the first WT rows
      if (tid < 14)  cb[tid] = c1n;
      if (tid < 196) cb[14 + tid] = c2n;
#pragma unroll
      for (int n = 0; n < 11; ++n) { int e = tid + n * 256; if (e < 2744) cb[210 + e] = a3[n]; }
    }
  }
}

// ---------------- scan pass C: row fixup S[r] := chen(Pfx[chunk], L[r]) -----
__global__ __launch_bounds__(256) void k_scanC(unsigned int* __restrict__ Sw,
                                               const float* __restrict__ Pfx,
                                               int rowStride, int RW) {
  int s = blockIdx.x, b = blockIdx.y, tid = threadIdx.x;
  int r0 = s * 16;
  int cnt = RW - r0; if (cnt > 16) cnt = 16;
  if (cnt <= 0) return;
  __shared__ float pa1[14], pa2[196], lb1[14], lb2[196];
  float pa3[11];
  int ia[11], i2[11], il2[11], ik[11];
#pragma unroll
  for (int n = 0; n < 11; ++n) {
    int e = tid + n * 256;
    ia[n] = e / 196; i2[n] = e / 14; il2[n] = e % 196; ik[n] = e % 14;
  }
  const float* P = Pfx + ((size_t)b * 16 + s) * SC1;
  if (tid < 14)  pa1[tid] = P[tid];
  if (tid < 196) pa2[tid] = P[14 + tid];
#pragma unroll
  for (int n = 0; n < 11; ++n) { int e = tid + n * 256; if (e < 2744) pa3[n] = P[210 + e]; }
  __syncthreads();
  unsigned int* Sb = Sw + ((size_t)b * rowStride + r0) * SC1;
  for (int j = 0; j < cnt; ++j) {
    unsigned int* row = Sb + (size_t)j * SC1;
    if (tid < 14)  lb1[tid] = unpack2(row[tid]);
    if (tid < 196) lb2[tid] = unpack2(row[14 + tid]);
    __syncthreads();
    if (tid < 14)  row[tid] = pack2(pa1[tid] + lb1[tid]);
    if (tid < 196) row[14 + tid] = pack2(pa2[tid] + lb2[tid] + pa1[tid / 14] * lb1[tid % 14]);
#pragma unroll
    for (int n = 0; n < 11; ++n) {
      int e = tid + n * 256;
      if (e < 2744) {
        float l3 = unpack2(row[210 + e]);
        row[210 + e] = pack2(pa3[n] + l3 + pa1[ia[n]] * lb2[il2[n]] + pa2[i2[n]] * lb1[ik[n]]);
      }
    }
    __syncthreads();
  }
}

// ---------------- MFMA GEMM (M-tile 64, 2 waves/block, 3-pass hi/lo) --------
// A[t][kf] = Swin[b][t*SC1 + kf] (im2col collapses; tail kf>=KFLAT hits W=0)
__global__ __launch_bounds__(128) void k_gemm2(const unsigned int* __restrict__ Swin,
                                               const unsigned int* __restrict__ Wp,
                                               const float* __restrict__ bias,
                                               float* __restrict__ C1,
                                               int rowStride, int WTcur) {
  int t0 = blockIdx.x * 64, b = blockIdx.y;
  int tid = threadIdx.x;
  int lane = tid & 63, wid = tid >> 6;
  __shared__ __align__(16) short Ah[64 * 64], Al[64 * 64], Bh[64 * 64], Bl[64 * 64];
  f32x16 acc0, acc1;
#pragma unroll
  for (int i = 0; i < 16; ++i) { acc0[i] = 0.f; acc1[i] = 0.f; }
  const unsigned int* Sb = Swin + (size_t)b * rowStride * SC1;
  const int c2 = (tid & 31) * 2;     // uint col within 64-wide chunk (even)
  const int rgrp = tid >> 5;         // 0..3
  const int kg = c2 >> 3, klo = c2 & 7;
  uint2 ra[16], rb[16];

  auto LOAD = [&](int ch) {
    int k0 = ch * 64;
#pragma unroll
    for (int p = 0; p < 16; ++p) {
      int m = p * 4 + rgrp;
      int t_l = t0 + m; if (t_l > WTcur - 1) t_l = WTcur - 1;
      ra[p] = *(const uint2*)(Sb + (size_t)t_l * SC1 + k0 + c2);
      rb[p] = *(const uint2*)(Wp + (size_t)m * KP + k0 + c2);
    }
  };
  auto STORE = [&]() {
#pragma unroll
    for (int p = 0; p < 16; ++p) {
      int m = p * 4 + rgrp;
      int eo = m * 64 + ((kg ^ (m & 7)) << 3) + klo;
      unsigned int ax = ra[p].x, ay = ra[p].y;
      *(unsigned int*)&Ah[eo] = (ay & 0xFFFF0000u) | (ax >> 16);
      *(unsigned int*)&Al[eo] = (ay << 16) | (ax & 0xFFFFu);
      unsigned int bx = rb[p].x, by = rb[p].y;
      *(unsigned int*)&Bh[eo] = (by & 0xFFFF0000u) | (bx >> 16);
      *(unsigned int*)&Bl[eo] = (by << 16) | (bx & 0xFFFFu);
    }
  };

  LOAD(0);
  STORE();
  __syncthreads();

  const int rA = wid * 32 + (lane & 31);
  const int o0 = lane & 31, o1 = o0 + 32;
  const int aswz = rA & 7, b0swz = o0 & 7, b1swz = o1 & 7;

  for (int ch = 0; ch < NKCH; ++ch) {
    if (ch + 1 < NKCH) LOAD(ch + 1);        // issue early (T14)
#pragma unroll
    for (int ks = 0; ks < 4; ++ks) {
      int kga = 2 * ks + (lane >> 5);
      const short8 ah  = *(const short8*)&Ah[rA * 64 + ((kga ^ aswz) << 3)];
      const short8 al  = *(const short8*)&Al[rA * 64 + ((kga ^ aswz) << 3)];
      const short8 b0h = *(const short8*)&Bh[o0 * 64 + ((kga ^ b0swz) << 3)];
      const short8 b0l = *(const short8*)&Bl[o0 * 64 + ((kga ^ b0swz) << 3)];
      const short8 b1h = *(const short8*)&Bh[o1 * 64 + ((kga ^ b1swz) << 3)];
      const short8 b1l = *(const short8*)&Bl[o1 * 64 + ((kga ^ b1swz) << 3)];
      acc0 = __builtin_amdgcn_mfma_f32_32x32x16_bf16(ah, b0h, acc0, 0, 0, 0);
      acc0 = __builtin_amdgcn_mfma_f32_32x32x16_bf16(ah, b0l, acc0, 0, 0, 0);
      acc0 = __builtin_amdgcn_mfma_f32_32x32x16_bf16(al, b0h, acc0, 0, 0, 0);
      acc1 = __builtin_amdgcn_mfma_f32_32x32x16_bf16(ah, b1h, acc1, 0, 0, 0);
      acc1 = __builtin_amdgcn_mfma_f32_32x32x16_bf16(ah, b1l, acc1, 0, 0, 0);
      acc1 = __builtin_amdgcn_mfma_f32_32x32x16_bf16(al, b1h, acc1, 0, 0, 0);
    }
    __syncthreads();
    if (ch + 1 < NKCH) { STORE(); __syncthreads(); }
  }

  float bia0 = bias[o0], bia1 = bias[o1];
#pragma unroll
  for (int q = 0; q < 16; ++q) {
    int crow = (q & 3) + 8 * (q >> 2) + 4 * (lane >> 5);
    int t_l = t0 + wid * 32 + crow;
    if (t_l < WTcur) {
      size_t o = ((size_t)b * TOUT + t_l) * OCH;
      C1[o + o0] = acc0[q] + bia0;
      C1[o + o1] = acc1[q] + bia1;
    }
  }
}

// ---------------- P2 window: relu(C1) @ w2 + b2, + time channel -------------
__global__ __launch_bounds__(256) void k_p2w(const float* __restrict__ C1,
                                             const float* __restrict__ w2,
                                             const float* __restrict__ b2,
                                             float* __restrict__ P2,
                                             int w0, int WTcur) {
  int warp = blockIdx.x * 4 + (threadIdx.x >> 6);
  int lane = threadIdx.x & 63;
  if (warp >= BATCH * WTcur) return;
  int b = warp / WTcur, t_l = warp % WTcur;
  int t = w0 + t_l;
  float v = fmaxf(C1[((size_t)b * TOUT + t_l) * OCH + lane], 0.f);
  float* o = P2 + ((size_t)b * TOUT + t) * 9;
#pragma unroll
  for (int oo = 0; oo < 8; ++oo) {
    float s = v * w2[oo * 64 + lane];
    for (int d = 32; d; d >>= 1) s += __shfl_xor(s, d);
    if (lane == oo) o[1 + oo] = s + b2[oo];
  }
  if (lane == 8) o[0] = (float)t * (1.0f / 246.0f);
}

// ---------------- final signature pass A: chunk totals ----------------------
__global__ __launch_bounds__(256) void k_sig2A(const float* __restrict__ P2,
                                               float* __restrict__ T2) {
  int ch = blockIdx.x, b = blockIdx.y, tid = threadIdx.x;
  int r0 = ch * 16;
  int steps = 246 - r0; if (steps > 16) steps = 16;
  const float* p = P2 + (size_t)b * TOUT * 9;
  __shared__ float a1s[9], a2s[81], vs[2][9], b2s[2][81];
  float a3[3];
  int ia[3], i2[3], il2[3], ik[3];
#pragma unroll
  for (int n = 0; n < 3; ++n) {
    int e = tid + n * 256;
    ia[n] = e / 81; i2[n] = e / 9; il2[n] = e % 81; ik[n] = e % 9;
  }
  {
    int r = r0;
    if (tid < 9) vs[0][tid] = p[(r + 1) * 9 + tid] - p[r * 9 + tid];
    if (tid < 81) {
      int j = tid / 9, k = tid % 9;
      b2s[0][tid] = 0.5f * (p[(r + 1) * 9 + j] - p[r * 9 + j])
                         * (p[(r + 1) * 9 + k] - p[r * 9 + k]);
    }
  }
  __syncthreads();
  for (int s = 0; s < steps; ++s) {
    int buf = s & 1, r = r0 + s;
    float c1n = 0.f, c2n = 0.f;
    if (s == 0) {
      if (tid < 9)  c1n = vs[buf][tid];
      if (tid < 81) c2n = b2s[buf][tid];
#pragma unroll
      for (int n = 0; n < 3; ++n) {
        int e = tid + n * 256;
        if (e < 729) a3[n] = vs[buf][ia[n]] * b2s[buf][il2[n]] * (1.f / 3.f);
      }
    } else {
#pragma unroll
      for (int n = 0; n < 3; ++n) {
        int e = tid + n * 256;
        if (e < 729)
          a3[n] += (a1s[ia[n]] + vs[buf][ia[n]] * (1.f / 3.f)) * b2s[buf][il2[n]]
                 + a2s[i2[n]] * vs[buf][ik[n]];
      }
      if (tid < 81) c2n = a2s[tid] + b2s[buf][tid] + a1s[tid / 9] * vs[buf][tid % 9];
      if (tid < 9)  c1n = a1s[tid] + vs[buf][tid];
    }
    __syncthreads();
    if (tid < 9)  a1s[tid] = c1n;
    if (tid < 81) a2s[tid] = c2n;
    if (s + 1 < steps) {
      int r2 = r + 1, nb = buf ^ 1;
      if (tid < 9) vs[nb][tid] = p[(r2 + 1) * 9 + tid] - p[r2 * 9 + tid];
      if (tid < 81) {
        int j = tid / 9, k = tid % 9;
        b2s[nb][tid] = 0.5f * (p[(r2 + 1) * 9 + j] - p[r2 * 9 + j])
                            * (p[(r2 + 1) * 9 + k] - p[r2 * 9 + k]);
      }
    }
    __syncthreads();
  }
  {
    float* tb = T2 + ((size_t)b * 16 + ch) * SC2;
    if (tid < 9)  tb[tid] = a1s[tid];
    if (tid < 81) tb[9 + tid] = a2s[tid];
#pragma unroll
    for (int n = 0; n < 3; ++n) {
      int e = tid + n * 256;
      if (e < 729) tb[90 + e] = a3[n];
    }
  }
}

// ---------------- final signature pass B: fold 16 totals --------------------
__global__ __launch_bounds__(256) void k_sig2B(const float* __restrict__ T2,
                                               float* __restrict__ sg) {
  int b = blockIdx.x, tid = threadIdx.x;
  __shared__ float a1s[9], a2s[81], b1s[9], b2s[81];
  float a3[3], b3[3];
  int ia[3], i2[3], il2[3], ik[3];
#pragma unroll
  for (int n = 0; n < 3; ++n) {
    int e = tid + n * 256;
    ia[n] = e / 81; i2[n] = e / 9; il2[n] = e % 81; ik[n] = e % 9;
  }
  const float* base = T2 + (size_t)b * 16 * SC2;
  if (tid < 9)  a1s[tid] = base[tid];
  if (tid < 81) a2s[tid] = base[9 + tid];
#pragma unroll
  for (int n = 0; n < 3; ++n) { int e = tid + n * 256; if (e < 729) a3[n] = base[90 + e]; }
  __syncthreads();
  for (int ch = 1; ch < 16; ++ch) {
    const float* sl = base + (size_t)ch * SC2;
    if (tid < 9)  b1s[tid] = sl[tid];
    if (tid < 81) b2s[tid] = sl[9 + tid];
#pragma unroll
    for (int n = 0; n < 3; ++n) { int e = tid + n * 256; if (e < 729) b3[n] = sl[90 + e]; }
    __syncthreads();
#pragma unroll
    for (int n = 0; n < 3; ++n) {
      int e = tid + n * 256;
      if (e < 729) a3[n] += b3[n] + a1s[ia[n]] * b2s[il2[n]] + a2s[i2[n]] * b1s[ik[n]];
    }
    float c1n = 0.f, c2n = 0.f;
    if (tid < 81) c2n = a2s[tid] + b2s[tid] + a1s[tid / 9] * b1s[tid % 9];
    if (tid < 9)  c1n = a1s[tid] + b1s[tid];
    __syncthreads();
    if (tid < 9)  a1s[tid] = c1n;
    if (tid < 81) a2s[tid] = c2n;
    __syncthreads();
  }
  float* o = sg + (size_t)b * SC2;
  if (tid < 9)  o[tid] = a1s[tid];
  if (tid < 81) o[9 + tid] = a2s[tid];
#pragma unroll
  for (int n = 0; n < 3; ++n) { int e = tid + n * 256; if (e < 729) o[90 + e] = a3[n]; }
}

// ---------------- linear + softmax -----------------------------------------
__global__ __launch_bounds__(64) void k_final(const float* __restrict__ sg,
                                              const float* __restrict__ lw,
                                              const float* __restrict__ lb,
                                              float* __restrict__ out) {
  int b = blockIdx.x, lane = threadIdx.x;
  float logit = -3.402823466e38f;
  if (lane < NSTK) {
    float s = lb[lane];
    const float* w = lw + (size_t)lane * SC2;
    const float* g = sg + (size_t)b * SC2;
    for (int c = 0; c < SC2; ++c) s += g[c] * w[c];
    logit = s;
  }
  float m = logit;
  for (int d = 32; d; d >>= 1) m = fmaxf(m, __shfl_xor(m, d));
  float e = (lane < NSTK) ? expf(logit - m) : 0.f;
  float sum = e;
  for (int d = 32; d; d >>= 1) sum += __shfl_xor(sum, d);
  if (lane < NSTK) out[(size_t)b * NSTK + lane] = e / sum;
}

// ---------------------------------------------------------------------------
extern "C" void kernel_launch(void* const* d_in, const int* in_sizes, int n_in,
                              void* d_out, int out_size, void* d_ws, size_t ws_size,
                              hipStream_t stream) {
  const float* x      = (const float*)d_in[0];
  const float* gamma  = (const float*)d_in[1];
  const float* beta   = (const float*)d_in[2];
  const float* a1w1   = (const float*)d_in[3];
  const float* a1b1   = (const float*)d_in[4];
  const float* a1w2   = (const float*)d_in[5];
  const float* a1b2   = (const float*)d_in[6];
  const float* a2w1   = (const float*)d_in[7];
  const float* a2b1   = (const float*)d_in[8];
  const float* a2w2   = (const float*)d_in[9];
  const float* a2b2   = (const float*)d_in[10];
  const float* lin_w  = (const float*)d_in[11];
  const float* lin_b  = (const float*)d_in[12];
  float* out = (float*)d_out;

  float* ws = (float*)d_ws;
  // fixed layout (float slots):
  float*        scale = ws;                       //      256
  float*        shift = ws + 256;                 //      256
  float*        P1    = ws + 512;                 //  451,584
  unsigned int* Wp    = (unsigned int*)(ws + 452096);      //  946,176
  float*        carry = ws + 1398272;             //  378,112
  float*        Pfx   = ws + 1776384;             // 16 x 378,112
  float*        P2    = ws + 7826176;             //  284,544
  float*        sig2  = ws + 8110720;             //  104,832
  float*        C1win = ws + 8215552;             // 2,023,424 (247x128x64)
  const size_t  off_Swin = 10238976;
  unsigned int* Swin  = (unsigned int*)(ws + off_Swin);
  float*        T2    = ws + off_Swin;            // reuses Swin (dead by then)

  size_t ws_floats = ws_size / 4;
  long avail = (long)ws_floats - (long)off_Swin - 64;   // 64-slot slack for tail reads
  long slot = (long)BATCH * SC1;                         // 378,112 per ring row
  int NRbuf = (int)(avail > 0 ? avail / slot : 0);
  if (NRbuf > 251) NRbuf = 251;
  if (NRbuf < 24)  NRbuf = 24;                           // ws proven >= ~315MB; safe
  int WT = (NRbuf >= 251) ? 247 : ((NRbuf - 4) / 16) * 16;
  int nwin = (TOUT + WT - 1) / WT;

  hipMemsetAsync(carry, 0, (size_t)slot * 4, stream);    // chen identity = zeros

  k_bn  <<<LSEQ, 256, 0, stream>>>(x, gamma, beta, scale, shift);
  k_aug1<<<(BATCH * L1P) / 256, 256, 0, stream>>>(x, scale, shift, a1w1, a1b1, a1w2, a1b2, P1);
  k_wt2 <<<(OCH * KP) / 256, 256, 0, stream>>>(a2w1, Wp);

  for (int w = 0; w < nwin; ++w) {
    int w0 = w * WT;
    int WTcur = TOUT - w0; if (WTcur > WT) WTcur = WT;
    int RW = WTcur + 4;
    int NC = (RW + 15) / 16;
    int NCC = (w + 1 < nwin) ? (WT / 16) : -2;
    k_scanA<<<dim3(NC, BATCH), 256, 0, stream>>>(P1, Swin, NRbuf, w0, RW);
    k_scanB<<<BATCH, 256, 0, stream>>>(Swin, Pfx, carry, NRbuf, RW, NC, NCC);
    k_scanC<<<dim3(NC, BATCH), 256, 0, stream>>>(Swin, Pfx, NRbuf, RW);
    int tiles = (WTcur + 63) / 64;
    k_gemm2<<<dim3(tiles, BATCH), 128, 0, stream>>>(Swin, Wp, a2b1, C1win, NRbuf, WTcur);
    int np2 = BATCH * WTcur;
    k_p2w<<<(np2 + 3) / 4, 256, 0, stream>>>(C1win, a2w2, a2b2, P2, w0, WTcur);
  }

  k_sig2A<<<dim3(16, BATCH), 256, 0, stream>>>(P2, T2);
  k_sig2B<<<BATCH, 256, 0, stream>>>(T2, sig2);
  k_final<<<BATCH, 64, 0, stream>>>(sig2, lin_w, lin_b, out);
}

// Round 5
// 1144.352 us; speedup vs baseline: 3.2346x; 2.6750x over previous
//
#include <hip/hip_runtime.h>
#include <cstdint>
#include <cstddef>

// ---------------------------------------------------------------------------
// PortOpt_DL_DeepSig round 5: round-4 kernels on round-3's adaptive windows.
//  - ws-adaptive t-windowed stream buffer (ws_size is UNKNOWN; round 2/4
//    proved ws < ~388 MB, round 3 proved the adaptive path works)
//  - fp32 stream; 3-pass parallel Chen scan per window (A local, B prefix+
//    carry, C parallel per-row fixup incl. chunk 0)
//  - GEMM: M64xN64, 4 waves, coalesced staging, trunc-split bf16 hi/lo,
//    3-pass MFMA (ah*bh + ah*bl + al*bh)
// ---------------------------------------------------------------------------

#define BATCH 128
#define LSEQ  256
#define CIN   8
#define L1P   252
#define NS1   251
#define SC1   2954    // 14 + 196 + 2744
#define TOUT  247
#define OCH   64
#define SC2   819     // 9 + 81 + 729
#define NSTK  50
#define KFLAT 14770   // 5*2954
#define KP    14784   // padded to 231*64
#define NKCH  231

typedef __attribute__((ext_vector_type(8))) short short8;
typedef __attribute__((ext_vector_type(16))) float f32x16;

// split 8 f32 into bf16 hi (truncation) + bf16 lo (RNE of remainder)
__device__ __forceinline__ void split8(float4 p, float4 q, uint4& hi, uint4& lo) {
  unsigned u0 = __float_as_uint(p.x), u1 = __float_as_uint(p.y);
  unsigned u2 = __float_as_uint(p.z), u3 = __float_as_uint(p.w);
  unsigned u4 = __float_as_uint(q.x), u5 = __float_as_uint(q.y);
  unsigned u6 = __float_as_uint(q.z), u7 = __float_as_uint(q.w);
  hi.x = __builtin_amdgcn_perm(u1, u0, 0x07060302u);
  hi.y = __builtin_amdgcn_perm(u3, u2, 0x07060302u);
  hi.z = __builtin_amdgcn_perm(u5, u4, 0x07060302u);
  hi.w = __builtin_amdgcn_perm(u7, u6, 0x07060302u);
  float r0 = p.x - __uint_as_float(u0 & 0xFFFF0000u);
  float r1 = p.y - __uint_as_float(u1 & 0xFFFF0000u);
  float r2 = p.z - __uint_as_float(u2 & 0xFFFF0000u);
  float r3 = p.w - __uint_as_float(u3 & 0xFFFF0000u);
  float r4 = q.x - __uint_as_float(u4 & 0xFFFF0000u);
  float r5 = q.y - __uint_as_float(u5 & 0xFFFF0000u);
  float r6 = q.z - __uint_as_float(u6 & 0xFFFF0000u);
  float r7 = q.w - __uint_as_float(u7 & 0xFFFF0000u);
  lo.x = __builtin_amdgcn_perm(__float_as_uint(r1), __float_as_uint(r0), 0x07060302u);
  lo.y = __builtin_amdgcn_perm(__float_as_uint(r3), __float_as_uint(r2), 0x07060302u);
  lo.z = __builtin_amdgcn_perm(__float_as_uint(r5), __float_as_uint(r4), 0x07060302u);
  lo.w = __builtin_amdgcn_perm(__float_as_uint(r7), __float_as_uint(r6), 0x07060302u);
}

// ---------------- BN stats ----------------
__global__ __launch_bounds__(256) void k_bn(const float* __restrict__ x,
                                            const float* __restrict__ gamma,
                                            const float* __restrict__ beta,
                                            float* __restrict__ scale,
                                            float* __restrict__ shift) {
  int l = blockIdx.x, tid = threadIdx.x;
  float s = 0.f, q = 0.f;
#pragma unroll
  for (int p = 0; p < 4; ++p) {
    int e = tid + p * 256;
    int b = e >> 3, c = e & 7;
    float v = x[((size_t)b * LSEQ + l) * CIN + c];
    s += v; q += v * v;
  }
  for (int d = 32; d; d >>= 1) { s += __shfl_xor(s, d); q += __shfl_xor(q, d); }
  __shared__ float ss[4], qq[4];
  int w = tid >> 6;
  if ((tid & 63) == 0) { ss[w] = s; qq[w] = q; }
  __syncthreads();
  if (tid == 0) {
    float S = ss[0] + ss[1] + ss[2] + ss[3];
    float Q = qq[0] + qq[1] + qq[2] + qq[3];
    float mean = S * (1.f / 1024.f);
    float var  = Q * (1.f / 1024.f) - mean * mean;
    float istd = 1.0f / sqrtf(var + 1e-5f);
    float sc = istd * gamma[l];
    scale[l] = sc;
    shift[l] = beta[l] - mean * sc;
  }
}

// ---------------- Augment 1: path1 (B, 252, 14) ----------------
__global__ __launch_bounds__(256) void k_aug1(const float* __restrict__ x,
                                              const float* __restrict__ scale,
                                              const float* __restrict__ shift,
                                              const float* __restrict__ w1,
                                              const float* __restrict__ b1,
                                              const float* __restrict__ w2,
                                              const float* __restrict__ b2,
                                              float* __restrict__ P1) {
  __shared__ float w1s[400], b1s[10], w2s[50], b2s[5];
  int tid = threadIdx.x;
  for (int i = tid; i < 400; i += 256) w1s[i] = w1[i];
  if (tid < 10) b1s[tid] = b1[tid];
  if (tid < 50) w2s[tid] = w2[tid];
  if (tid < 5)  b2s[tid] = b2[tid];
  __syncthreads();
  int g = blockIdx.x * 256 + tid;
  if (g >= BATCH * L1P) return;
  int b = g / L1P, t = g % L1P;
  float xn[5][8];
#pragma unroll
  for (int k = 0; k < 5; ++k) {
    int l = t + k;
    float sc = scale[l], sh = shift[l];
#pragma unroll
    for (int c = 0; c < 8; ++c)
      xn[k][c] = x[((size_t)b * LSEQ + l) * CIN + c] * sc + sh;
  }
  float r10[10];
#pragma unroll
  for (int co = 0; co < 10; ++co) {
    float s = b1s[co];
#pragma unroll
    for (int c = 0; c < 8; ++c)
#pragma unroll
      for (int k = 0; k < 5; ++k)
        s += xn[k][c] * w1s[co * 40 + c * 5 + k];
    r10[co] = fmaxf(s, 0.f);
  }
  float* o = P1 + ((size_t)b * L1P + t) * 14;
#pragma unroll
  for (int c = 0; c < 8; ++c) o[c] = xn[4][c];
  o[8] = (float)t * (1.0f / 251.0f);
#pragma unroll
  for (int oo = 0; oo < 5; ++oo) {
    float s = b2s[oo];
#pragma unroll
    for (int co = 0; co < 10; ++co) s += r10[co] * w2s[oo * 10 + co];
    o[9 + oo] = s;
  }
}

// ---------------- W -> [o][kflat] f32, zero padded ----------------
__global__ __launch_bounds__(256) void k_wtf(const float* __restrict__ w,
                                             float* __restrict__ Wf) {
  int idx = blockIdx.x * 256 + threadIdx.x;
  if (idx >= OCH * KP) return;
  int o = idx / KP, kf = idx % KP;
  float v = 0.f;
  if (kf < KFLAT) {
    int tap = kf / SC1, c = kf % SC1;
    v = w[((size_t)o * SC1 + c) * 5 + tap];
  }
  Wf[idx] = v;
}

// ---------------- scan pass A: window chunk-local signatures ---------------
__global__ __launch_bounds__(256) void k_scanA(const float* __restrict__ P1,
                                               float* __restrict__ Sw,
                                               int NRbuf, int w0, int RW) {
  int s = blockIdx.x, b = blockIdx.y, tid = threadIdx.x;
  int r0 = s * 16;
  int cnt = RW - r0; if (cnt > 16) cnt = 16;
  if (cnt <= 0) return;
  const float* p = P1 + (size_t)b * L1P * 14 + (size_t)(w0 + r0) * 14;
  float* Sb = Sw + ((size_t)b * NRbuf + r0) * SC1;
  __shared__ float a1s[14], a2s[196], vs[2][14], b2s[2][196];
  float a3[11];
  int ia[11], i2[11], il2[11], ik[11];
#pragma unroll
  for (int n = 0; n < 11; ++n) {
    int e = tid + n * 256;
    ia[n] = e / 196; i2[n] = e / 14; il2[n] = e % 196; ik[n] = e % 14;
  }
  if (tid < 14) vs[0][tid] = p[14 + tid] - p[tid];
  if (tid < 196) {
    int j = tid / 14, k = tid % 14;
    b2s[0][tid] = 0.5f * (p[14 + j] - p[j]) * (p[14 + k] - p[k]);
  }
  __syncthreads();
  for (int j = 0; j < cnt; ++j) {
    int buf = j & 1;
    float c1n = 0.f, c2n = 0.f;
    if (j == 0) {
      if (tid < 14)  c1n = vs[buf][tid];
      if (tid < 196) c2n = b2s[buf][tid];
#pragma unroll
      for (int n = 0; n < 11; ++n) {
        int e = tid + n * 256;
        if (e < 2744) a3[n] = vs[buf][ia[n]] * b2s[buf][il2[n]] * (1.f / 3.f);
      }
    } else {
#pragma unroll
      for (int n = 0; n < 11; ++n) {
        int e = tid + n * 256;
        if (e < 2744)
          a3[n] += (a1s[ia[n]] + vs[buf][ia[n]] * (1.f / 3.f)) * b2s[buf][il2[n]]
                 + a2s[i2[n]] * vs[buf][ik[n]];
      }
      if (tid < 196) c2n = a2s[tid] + b2s[buf][tid] + a1s[tid / 14] * vs[buf][tid % 14];
      if (tid < 14)  c1n = a1s[tid] + vs[buf][tid];
    }
    __syncthreads();
    if (tid < 14)  a1s[tid] = c1n;
    if (tid < 196) a2s[tid] = c2n;
    {
      float* o = Sb + (size_t)j * SC1;
      if (tid < 14)  o[tid] = c1n;
      if (tid < 196) o[14 + tid] = c2n;
#pragma unroll
      for (int n = 0; n < 11; ++n) {
        int e = tid + n * 256;
        if (e < 2744) o[210 + e] = a3[n];
      }
    }
    if (j + 1 < cnt) {
      int nb = buf ^ 1;
      const float* pj = p + (size_t)(j + 1) * 14;
      if (tid < 14) vs[nb][tid] = pj[14 + tid] - pj[tid];
      if (tid < 196) {
        int jj = tid / 14, kk = tid % 14;
        b2s[nb][tid] = 0.5f * (pj[14 + jj] - pj[jj]) * (pj[14 + kk] - pj[kk]);
      }
    }
    __syncthreads();
  }
}

// ---------------- scan pass B: prefix of chunk totals + carry ---------------
__global__ __launch_bounds__(256) void k_scanB(const float* __restrict__ Sw,
                                               float* __restrict__ Pfx,
                                               float* __restrict__ carry,
                                               int NRbuf, int RW, int NC, int NCC) {
  int b = blockIdx.x, tid = threadIdx.x;
  __shared__ float a1s[14], a2s[196], b1s[14], b2s[196];
  float a3[11], b3[11];
  int ia[11], i2[11], il2[11], ik[11];
#pragma unroll
  for (int n = 0; n < 11; ++n) {
    int e = tid + n * 256;
    ia[n] = e / 196; i2[n] = e / 14; il2[n] = e % 196; ik[n] = e % 14;
  }
  const float* Sb = Sw + (size_t)b * NRbuf * SC1;
  float* cb = carry + (size_t)b * SC1;
  if (tid < 14)  a1s[tid] = cb[tid];
  if (tid < 196) a2s[tid] = cb[14 + tid];
#pragma unroll
  for (int n = 0; n < 11; ++n) { int e = tid + n * 256; if (e < 2744) a3[n] = cb[210 + e]; }
  __syncthreads();
  for (int s = 0; s < NC; ++s) {
    int cnt = RW - s * 16; if (cnt > 16) cnt = 16;
    const float* tr = Sb + (size_t)(s * 16 + cnt - 1) * SC1;
    if (tid < 14)  b1s[tid] = tr[tid];
    if (tid < 196) b2s[tid] = tr[14 + tid];
#pragma unroll
    for (int n = 0; n < 11; ++n) { int e = tid + n * 256; if (e < 2744) b3[n] = tr[210 + e]; }
    __syncthreads();
    // Pfx[s] := prefix BEFORE absorbing chunk s
    float* ps = Pfx + ((size_t)b * 16 + s) * SC1;
    if (tid < 14)  ps[tid] = a1s[tid];
    if (tid < 196) ps[14 + tid] = a2s[tid];
#pragma unroll
    for (int n = 0; n < 11; ++n) { int e = tid + n * 256; if (e < 2744) ps[210 + e] = a3[n]; }
    // a := chen(a, b)
#pragma unroll
    for (int n = 0; n < 11; ++n) {
      int e = tid + n * 256;
      if (e < 2744) a3[n] += b3[n] + a1s[ia[n]] * b2s[il2[n]] + a2s[i2[n]] * b1s[ik[n]];
    }
    float c1n = 0.f, c2n = 0.f;
    if (tid < 196) c2n = a2s[tid] + b2s[tid] + a1s[tid / 14] * b1s[tid % 14];
    if (tid < 14)  c1n = a1s[tid] + b1s[tid];
    __syncthreads();
    if (tid < 14)  a1s[tid] = c1n;
    if (tid < 196) a2s[tid] = c2n;
    if (s == NCC - 1) {   // carry = signature through first WT rows of window
      if (tid < 14)  cb[tid] = c1n;
      if (tid < 196) cb[14 + tid] = c2n;
#pragma unroll
      for (int n = 0; n < 11; ++n) { int e = tid + n * 256; if (e < 2744) cb[210 + e] = a3[n]; }
    }
  }
}

// ---------------- scan pass C: parallel row fixup (incl. chunk 0) -----------
__global__ __launch_bounds__(256) void k_scanC3(float* __restrict__ Sw,
                                                const float* __restrict__ Pfx,
                                                int NRbuf, int RW) {
  int s = blockIdx.x, b = blockIdx.y, tid = threadIdx.x;
  int r0 = s * 16;
  int rows = RW - r0; if (rows > 16) rows = 16;
  if (rows <= 0) return;
  __shared__ float pa[SC1];
  __shared__ float lb[4][216];
  const float* P = Pfx + ((size_t)b * 16 + s) * SC1;
  for (int i = tid; i < SC1; i += 256) pa[i] = P[i];
  __syncthreads();
  int w = tid >> 6, lane = tid & 63;
  float* base = Sw + ((size_t)b * NRbuf + r0) * SC1;
#pragma unroll
  for (int j = 0; j < 4; ++j) {
    int rr = w + j * 4;
    if (rr < rows) {
      float* row = base + (size_t)rr * SC1;
      if (lane < 53) {
        float4 v = *(const float4*)(row + lane * 4);
        *(float4*)&lb[w][lane * 4] = v;
      }
      asm volatile("s_waitcnt lgkmcnt(0)" ::: "memory");
      for (int c = lane; c < SC1; c += 64) {
        float v = row[c];
        float f;
        if (c < 14) {
          f = pa[c] + v;
        } else if (c < 210) {
          int e = c - 14;
          f = pa[c] + v + pa[e / 14] * lb[w][e % 14];
        } else {
          int e = c - 210;
          int i3 = e / 196, rjk = e - i3 * 196;
          int i2 = e / 14,  kk  = e - i2 * 14;
          f = pa[c] + v + pa[i3] * lb[w][14 + rjk] + pa[14 + i2] * lb[w][kk];
        }
        row[c] = f;
      }
    }
  }
}

// ---------------- MFMA GEMM: M64 x N64 tile, 4 waves (2M x 2N) --------------
__global__ __launch_bounds__(256) void k_gemm3(const float* __restrict__ Sw,
                                               const float* __restrict__ Wf,
                                               const float* __restrict__ bias,
                                               float* __restrict__ C1,
                                               int NRbuf, int w0, int WTcur) {
  const int t0 = blockIdx.x * 64;
  const int b  = blockIdx.y;
  const int tid = threadIdx.x, lane = tid & 63;
  __shared__ __align__(16) short Ah[4096], Al[4096], Bh[4096], Bl[4096];
  f32x16 acc;
#pragma unroll
  for (int i = 0; i < 16; ++i) acc[i] = 0.f;

  const float* Sb = Sw + (size_t)b * ((size_t)NRbuf * SC1);
  const int arow = tid >> 2;
  const int g0 = tid & 3, g1 = g0 + 4;
  const int at = min(t0 + arow, WTcur - 1);
  const float* aP = Sb + (size_t)at * SC1;
  const float* bP = Wf + (size_t)arow * KP;
  const int sw = arow & 7;
  const int offA0 = arow * 64 + ((g0 ^ sw) << 3);
  const int offA1 = arow * 64 + ((g1 ^ sw) << 3);
  float4 a0, a1, a2, a3, w0v, w1v, w2v, w3v;

  auto LOADCH = [&](int k0) {
    a0 = *(const float4*)(aP + k0 + g0 * 8);
    a1 = *(const float4*)(aP + k0 + g0 * 8 + 4);
    a2 = *(const float4*)(aP + k0 + g1 * 8);
    a3 = *(const float4*)(aP + k0 + g1 * 8 + 4);
    w0v = *(const float4*)(bP + k0 + g0 * 8);
    w1v = *(const float4*)(bP + k0 + g0 * 8 + 4);
    w2v = *(const float4*)(bP + k0 + g1 * 8);
    w3v = *(const float4*)(bP + k0 + g1 * 8 + 4);
  };
  auto STORECH = [&]() {
    uint4 hi, lo;
    split8(a0, a1, hi, lo);
    *(uint4*)&Ah[offA0] = hi; *(uint4*)&Al[offA0] = lo;
    split8(a2, a3, hi, lo);
    *(uint4*)&Ah[offA1] = hi; *(uint4*)&Al[offA1] = lo;
    split8(w0v, w1v, hi, lo);
    *(uint4*)&Bh[offA0] = hi; *(uint4*)&Bl[offA0] = lo;
    split8(w2v, w3v, hi, lo);
    *(uint4*)&Bh[offA1] = hi; *(uint4*)&Bl[offA1] = lo;
  };

  const int rowA = ((tid >> 6) & 1) * 32 + (lane & 31);
  const int rowB = (tid >> 7) * 32 + (lane & 31);
  const int swA = rowA & 7, swB = rowB & 7;
  const int baseA = rowA * 64, baseB = rowB * 64;

  LOADCH(0);
  STORECH();
  __syncthreads();

  for (int ch = 0; ch < NKCH; ++ch) {
    if (ch + 1 < NKCH) LOADCH((ch + 1) * 64);   // issue early, write late (T14)
#pragma unroll
    for (int ks = 0; ks < 4; ++ks) {
      const int kga = 2 * ks + (lane >> 5);
      const short8 ah = *(const short8*)&Ah[baseA + ((kga ^ swA) << 3)];
      const short8 al = *(const short8*)&Al[baseA + ((kga ^ swA) << 3)];
      const short8 bh = *(const short8*)&Bh[baseB + ((kga ^ swB) << 3)];
      const short8 bl = *(const short8*)&Bl[baseB + ((kga ^ swB) << 3)];
      acc = __builtin_amdgcn_mfma_f32_32x32x16_bf16(ah, bh, acc, 0, 0, 0);
      acc = __builtin_amdgcn_mfma_f32_32x32x16_bf16(ah, bl, acc, 0, 0, 0);
      acc = __builtin_amdgcn_mfma_f32_32x32x16_bf16(al, bh, acc, 0, 0, 0);
    }
    __syncthreads();
    if (ch + 1 < NKCH) { STORECH(); __syncthreads(); }
  }

  const float bia = bias[rowB];
  const int mbase = t0 + ((tid >> 6) & 1) * 32;
#pragma unroll
  for (int q = 0; q < 16; ++q) {
    int crow = (q & 3) + 8 * (q >> 2) + 4 * (lane >> 5);
    int t_l = mbase + crow;
    if (t_l < WTcur)
      C1[((size_t)b * TOUT + w0 + t_l) * OCH + rowB] = acc[q] + bia;
  }
}

// ---------------- P2: relu(C1) @ w2 + b2, plus time channel ----------------
__global__ __launch_bounds__(256) void k_p2(const float* __restrict__ C1,
                                            const float* __restrict__ w2,
                                            const float* __restrict__ b2,
                                            float* __restrict__ P2) {
  int warp = blockIdx.x * 4 + (threadIdx.x >> 6);
  int lane = threadIdx.x & 63;
  int b = warp / TOUT, t = warp % TOUT;
  float v = fmaxf(C1[((size_t)b * TOUT + t) * OCH + lane], 0.f);
  float* o = P2 + ((size_t)b * TOUT + t) * 9;
#pragma unroll
  for (int oo = 0; oo < 8; ++oo) {
    float s = v * w2[oo * 64 + lane];
    for (int d = 32; d; d >>= 1) s += __shfl_xor(s, d);
    if (lane == oo) o[1 + oo] = s + b2[oo];
  }
  if (lane == 8) o[0] = (float)t * (1.0f / 246.0f);
}

// ---------------- final signature pass A: chunk totals ----------------------
__global__ __launch_bounds__(256) void k_sig2A(const float* __restrict__ P2,
                                               float* __restrict__ T2) {
  int ch = blockIdx.x, b = blockIdx.y, tid = threadIdx.x;
  int r0 = ch * 16;
  int steps = 246 - r0; if (steps > 16) steps = 16;
  const float* p = P2 + (size_t)b * TOUT * 9;
  __shared__ float a1s[9], a2s[81], vs[2][9], b2s[2][81];
  float a3[3];
  int ia[3], i2[3], il2[3], ik[3];
#pragma unroll
  for (int n = 0; n < 3; ++n) {
    int e = tid + n * 256;
    ia[n] = e / 81; i2[n] = e / 9; il2[n] = e % 81; ik[n] = e % 9;
  }
  {
    int r = r0;
    if (tid < 9) vs[0][tid] = p[(r + 1) * 9 + tid] - p[r * 9 + tid];
    if (tid < 81) {
      int j = tid / 9, k = tid % 9;
      b2s[0][tid] = 0.5f * (p[(r + 1) * 9 + j] - p[r * 9 + j])
                         * (p[(r + 1) * 9 + k] - p[r * 9 + k]);
    }
  }
  __syncthreads();
  for (int s = 0; s < steps; ++s) {
    int buf = s & 1, r = r0 + s;
    float c1n = 0.f, c2n = 0.f;
    if (s == 0) {
      if (tid < 9)  c1n = vs[buf][tid];
      if (tid < 81) c2n = b2s[buf][tid];
#pragma unroll
      for (int n = 0; n < 3; ++n) {
        int e = tid + n * 256;
        if (e < 729) a3[n] = vs[buf][ia[n]] * b2s[buf][il2[n]] * (1.f / 3.f);
      }
    } else {
#pragma unroll
      for (int n = 0; n < 3; ++n) {
        int e = tid + n * 256;
        if (e < 729)
          a3[n] += (a1s[ia[n]] + vs[buf][ia[n]] * (1.f / 3.f)) * b2s[buf][il2[n]]
                 + a2s[i2[n]] * vs[buf][ik[n]];
      }
      if (tid < 81) c2n = a2s[tid] + b2s[buf][tid] + a1s[tid / 9] * vs[buf][tid % 9];
      if (tid < 9)  c1n = a1s[tid] + vs[buf][tid];
    }
    __syncthreads();
    if (tid < 9)  a1s[tid] = c1n;
    if (tid < 81) a2s[tid] = c2n;
    if (s + 1 < steps) {
      int r2 = r + 1, nb = buf ^ 1;
      if (tid < 9) vs[nb][tid] = p[(r2 + 1) * 9 + tid] - p[r2 * 9 + tid];
      if (tid < 81) {
        int j = tid / 9, k = tid % 9;
        b2s[nb][tid] = 0.5f * (p[(r2 + 1) * 9 + j] - p[r2 * 9 + j])
                            * (p[(r2 + 1) * 9 + k] - p[r2 * 9 + k]);
      }
    }
    __syncthreads();
  }
  {
    float* tb = T2 + ((size_t)b * 16 + ch) * SC2;
    if (tid < 9)  tb[tid] = a1s[tid];
    if (tid < 81) tb[9 + tid] = a2s[tid];
#pragma unroll
    for (int n = 0; n < 3; ++n) {
      int e = tid + n * 256;
      if (e < 729) tb[90 + e] = a3[n];
    }
  }
}

// ---------------- final signature pass B: fold 16 totals --------------------
__global__ __launch_bounds__(256) void k_sig2B(const float* __restrict__ T2,
                                               float* __restrict__ sg) {
  int b = blockIdx.x, tid = threadIdx.x;
  __shared__ float a1s[9], a2s[81], b1s[9], b2s[81];
  float a3[3], b3[3];
  int ia[3], i2[3], il2[3], ik[3];
#pragma unroll
  for (int n = 0; n < 3; ++n) {
    int e = tid + n * 256;
    ia[n] = e / 81; i2[n] = e / 9; il2[n] = e % 81; ik[n] = e % 9;
  }
  const float* base = T2 + (size_t)b * 16 * SC2;
  if (tid < 9)  a1s[tid] = base[tid];
  if (tid < 81) a2s[tid] = base[9 + tid];
#pragma unroll
  for (int n = 0; n < 3; ++n) { int e = tid + n * 256; if (e < 729) a3[n] = base[90 + e]; }
  __syncthreads();
  for (int ch = 1; ch < 16; ++ch) {
    const float* sl = base + (size_t)ch * SC2;
    if (tid < 9)  b1s[tid] = sl[tid];
    if (tid < 81) b2s[tid] = sl[9 + tid];
#pragma unroll
    for (int n = 0; n < 3; ++n) { int e = tid + n * 256; if (e < 729) b3[n] = sl[90 + e]; }
    __syncthreads();
#pragma unroll
    for (int n = 0; n < 3; ++n) {
      int e = tid + n * 256;
      if (e < 729) a3[n] += b3[n] + a1s[ia[n]] * b2s[il2[n]] + a2s[i2[n]] * b1s[ik[n]];
    }
    float c1n = 0.f, c2n = 0.f;
    if (tid < 81) c2n = a2s[tid] + b2s[tid] + a1s[tid / 9] * b1s[tid % 9];
    if (tid < 9)  c1n = a1s[tid] + b1s[tid];
    __syncthreads();
    if (tid < 9)  a1s[tid] = c1n;
    if (tid < 81) a2s[tid] = c2n;
    __syncthreads();
  }
  float* o = sg + (size_t)b * SC2;
  if (tid < 9)  o[tid] = a1s[tid];
  if (tid < 81) o[9 + tid] = a2s[tid];
#pragma unroll
  for (int n = 0; n < 3; ++n) { int e = tid + n * 256; if (e < 729) o[90 + e] = a3[n]; }
}

// ---------------- linear + softmax -----------------------------------------
__global__ __launch_bounds__(64) void k_final(const float* __restrict__ sg,
                                              const float* __restrict__ lw,
                                              const float* __restrict__ lb,
                                              float* __restrict__ out) {
  int b = blockIdx.x, lane = threadIdx.x;
  float logit = -3.402823466e38f;
  if (lane < NSTK) {
    float s = lb[lane];
    const float* w = lw + (size_t)lane * SC2;
    const float* g = sg + (size_t)b * SC2;
    for (int c = 0; c < SC2; ++c) s += g[c] * w[c];
    logit = s;
  }
  float m = logit;
  for (int d = 32; d; d >>= 1) m = fmaxf(m, __shfl_xor(m, d));
  float e = (lane < NSTK) ? expf(logit - m) : 0.f;
  float sum = e;
  for (int d = 32; d; d >>= 1) sum += __shfl_xor(sum, d);
  if (lane < NSTK) out[(size_t)b * NSTK + lane] = e / sum;
}

// ---------------------------------------------------------------------------
extern "C" void kernel_launch(void* const* d_in, const int* in_sizes, int n_in,
                              void* d_out, int out_size, void* d_ws, size_t ws_size,
                              hipStream_t stream) {
  const float* x      = (const float*)d_in[0];
  const float* gamma  = (const float*)d_in[1];
  const float* beta   = (const float*)d_in[2];
  const float* a1w1   = (const float*)d_in[3];
  const float* a1b1   = (const float*)d_in[4];
  const float* a1w2   = (const float*)d_in[5];
  const float* a1b2   = (const float*)d_in[6];
  const float* a2w1   = (const float*)d_in[7];
  const float* a2b1   = (const float*)d_in[8];
  const float* a2w2   = (const float*)d_in[9];
  const float* a2b2   = (const float*)d_in[10];
  const float* lin_w  = (const float*)d_in[11];
  const float* lin_b  = (const float*)d_in[12];
  float* out = (float*)d_out;

  float* ws = (float*)d_ws;
  // fixed prefix (floats): ends at 10,238,976 (= 41.0 MB); Swin adaptive after
  float* scale = ws;                        //       256
  float* shift = ws + 256;                  //       256
  float* P1    = ws + 512;                  //   451,584
  float* Wf    = ws + 452096;               //   946,176
  float* carry = ws + 1398272;              //   378,112
  float* Pfx   = ws + 1776384;              // 6,049,792 (16 x 378,112)
  float* P2    = ws + 7826176;              //   284,544
  float* sig2  = ws + 8110720;              //   104,832
  float* C1    = ws + 8215552;              // 2,023,424
  const size_t off_Swin = 10238976;
  float* Swin  = ws + off_Swin;
  float* T2    = Pfx;                       // Pfx dead after last scanC

  size_t ws_floats = ws_size / 4;
  long avail = (long)ws_floats - (long)off_Swin - 64;   // 64-float slack for tail reads
  long slot = (long)BATCH * SC1;                         // 378,112 floats per buffered row
  int NRbuf = (int)(avail > 0 ? avail / slot : 0);
  if (NRbuf > 251) NRbuf = 251;
  if (NRbuf < 24)  NRbuf = 24;      // min footprint 77 MB — proven safe (round 3)
  int WT = (NRbuf >= 251) ? 247 : ((NRbuf - 4) / 16) * 16;
  int nwin = (TOUT + WT - 1) / WT;

  hipMemsetAsync(carry, 0, (size_t)slot * 4, stream);   // chen identity = zeros

  k_bn  <<<LSEQ, 256, 0, stream>>>(x, gamma, beta, scale, shift);
  k_aug1<<<(BATCH * L1P) / 256, 256, 0, stream>>>(x, scale, shift, a1w1, a1b1, a1w2, a1b2, P1);
  k_wtf <<<(OCH * KP) / 256, 256, 0, stream>>>(a2w1, Wf);

  for (int w = 0; w < nwin; ++w) {
    int w0 = w * WT;
    int WTcur = TOUT - w0; if (WTcur > WT) WTcur = WT;
    int RW = WTcur + 4;
    int NC = (RW + 15) / 16;
    int NCC = (w + 1 < nwin) ? (WT / 16) : -2;
    k_scanA<<<dim3(NC, BATCH), 256, 0, stream>>>(P1, Swin, NRbuf, w0, RW);
    k_scanB<<<BATCH, 256, 0, stream>>>(Swin, Pfx, carry, NRbuf, RW, NC, NCC);
    k_scanC3<<<dim3(NC, BATCH), 256, 0, stream>>>(Swin, Pfx, NRbuf, RW);
    int tiles = (WTcur + 63) / 64;
    k_gemm3<<<dim3(tiles, BATCH), 256, 0, stream>>>(Swin, Wf, a2b1, C1, NRbuf, w0, WTcur);
  }

  k_p2   <<<(BATCH * TOUT) / 4, 256, 0, stream>>>(C1, a2w2, a2b2, P2);
  k_sig2A<<<dim3(16, BATCH), 256, 0, stream>>>(P2, T2);
  k_sig2B<<<BATCH, 256, 0, stream>>>(T2, sig2);
  k_final<<<BATCH, 64, 0, stream>>>(sig2, lin_w, lin_b, out);
}